// Round 8
// baseline (491.914 us; speedup 1.0000x reference)
//
#include <hip/hip_runtime.h>

typedef float f32x4 __attribute__((ext_vector_type(4)));
typedef __bf16 bf16x8 __attribute__((ext_vector_type(8)));
typedef unsigned short u16x8 __attribute__((ext_vector_type(8)));
typedef unsigned int u32x4 __attribute__((ext_vector_type(4)));

#define NBH 16
#define NSEQ 4096
#define DH 64

__device__ __forceinline__ unsigned int cvtpk(float lo, float hi) {
  unsigned int r;
  asm("v_cvt_pk_bf16_f32 %0, %1, %2" : "=v"(r) : "v"(lo), "v"(hi));
  return r;
}
__device__ __forceinline__ bf16x8 pk8(const float* f) {
  union { unsigned int u[4]; bf16x8 b; } x;
#pragma unroll
  for (int i = 0; i < 4; ++i) x.u[i] = cvtpk(f[2 * i], f[2 * i + 1]);
  return x.b;
}
__device__ __forceinline__ float bf2f(unsigned short h) {
  return __uint_as_float(((unsigned int)h) << 16);
}

// Light barrier: drain LDS ops only; global loads/stores stay in flight.
__device__ __forceinline__ void lbar() {
  __builtin_amdgcn_sched_barrier(0);
  asm volatile("s_waitcnt lgkmcnt(0)" ::: "memory");
  __builtin_amdgcn_s_barrier();
  __builtin_amdgcn_sched_barrier(0);
}

// Fused causal SDPA. Block = complementary 64-row q-tiles {qa=qt, qb=63-qt};
// waves 0-3 tile A, waves 4-7 tile B. Pass 1 (denominators): barrier-free,
// K direct from global, zero-fill interleaved. Pass 2: R4-proven protocol
// (K+V double-buffered LDS, 1 lbar/iter, immediate PV), attn stored as
// dwordx4 via wave-private Pl readback (bf16-rounded attn, R1-proven).
__global__ __launch_bounds__(512, 4) void sdpa_fused(
    const float* __restrict__ qg, const float* __restrict__ kg,
    const float* __restrict__ vg, float* __restrict__ outg) {
  const int bid = blockIdx.x;
  const int xcd = bid & 7;
  const int ii = bid >> 3;                    // 0..63
  const int hh = ii >> 5;                     // head within XCD
  const int qt = (ii < 32) ? ii : 63 - ii;    // co-resident pair -> complementary
  const int b = 2 * xcd + hh;
  const int qa = qt, qb = 63 - qt;

  const int tid = threadIdx.x;
  const int w = tid >> 6, lane = tid & 63;
  const int g = lane >> 4, c = lane & 15;
  const int grp = w >> 2;                 // 0: tile A, 1: tile B
  const int wr0 = 16 * (w & 3);
  const int qrw = (grp ? qb : qa) * 64;   // wave's q-tile row base
  const int kmax = grp ? qb : qa;         // last K-tile this wave computes
  const int pOff = 16 * w;                // wave-private Pl rows

  const float* qbp = qg + (size_t)b * NSEQ * DH;
  const float* kbp = kg + (size_t)b * NSEQ * DH;
  const float* vbp = vg + (size_t)b * NSEQ * DH;
  float* outb = outg + (size_t)b * NSEQ * DH;
  float* attnb = outg + (size_t)NBH * NSEQ * DH + (size_t)b * NSEQ * NSEQ;

  __shared__ unsigned short Kl[2][64][72];
  __shared__ unsigned int Vt[2][64][37];   // u32 = {bf16 V[2p][d], bf16 V[2p+1][d]}
  __shared__ unsigned short Pl[128][72];   // wave-private 16-row slabs

  // ---- Q fragments: row = qrw+wr0+c, k = 32ks+8g+e ----
  bf16x8 aq[2];
  {
    const float* qrow = qbp + (size_t)(qrw + wr0 + c) * DH;
#pragma unroll
    for (int ks = 0; ks < 2; ++ks) {
      float f[8];
      *(float4*)f = *(const float4*)(qrow + 32 * ks + 8 * g);
      *(float4*)(f + 4) = *(const float4*)(qrow + 32 * ks + 8 * g + 4);
      aq[ks] = pk8(f);
    }
  }

  // ---- pass-1 direct QK^T batch: K frags from global, 4 MFMAs ----
  auto qk_batch = [&](int kt, int ks, f32x4* acc) {
    float4 ka[4], kb2[4];
#pragma unroll
    for (int ct = 0; ct < 4; ++ct) {
      const float* s = kbp + (size_t)(kt * 64 + 16 * ct + c) * DH + 32 * ks + 8 * g;
      ka[ct] = ((const float4*)s)[0];
      kb2[ct] = ((const float4*)s)[1];
    }
#pragma unroll
    for (int ct = 0; ct < 4; ++ct) {
      float f[8];
      *(float4*)f = ka[ct];
      *(float4*)(f + 4) = kb2[ct];
      acc[ct] = __builtin_amdgcn_mfma_f32_16x16x32_bf16(aq[ks], pk8(f), acc[ct], 0, 0, 0);
    }
  };

  // ---- zero-fill: 4032 chunks (64 cols) per block, 32 chunks/step ----
  const int myChunk = 4 * w + g;
  const int fc4 = c;
  auto fillStep = [&](int s) {
    const int cid = s * 32 + myChunk;     // 0..4031
    const int pr = cid / 63;
    const int t = cid - pr * 63;
    int row, col64;
    if (t < 63 - qa) { row = qa * 64 + pr; col64 = qa + 1 + t; }
    else             { row = qb * 64 + pr; col64 = t + 1; }
    const float4 z = {0.f, 0.f, 0.f, 0.f};
    *(float4*)(attnb + (size_t)row * NSEQ + col64 * 64 + fc4 * 4) = z;
  };

  // ---- staging maps (pass 2) ----
  const int kj = tid >> 3, kcs = tid & 7;   // K: row kj, 8-float chunk
  const int vp = tid >> 4, dch = tid & 15;  // V: row-pair vp, 4-dim chunk
  float kf[8], vf0[4], vf1[4];

  auto loadK = [&](int kt) {
    const float* s = kbp + (size_t)(kt * 64 + kj) * DH + kcs * 8;
    *(float4*)kf = ((const float4*)s)[0];
    *(float4*)(kf + 4) = ((const float4*)s)[1];
  };
  auto writeK = [&](int cur) {
    u32x4 u;
#pragma unroll
    for (int i = 0; i < 4; ++i) u[i] = cvtpk(kf[2 * i], kf[2 * i + 1]);
    *(u32x4*)&Kl[cur][kj][kcs * 8] = u;
  };
  auto loadV = [&](int kt) {
    const float* s0 = vbp + (size_t)(kt * 64 + 2 * vp) * DH + dch * 4;
    *(float4*)vf0 = *(const float4*)s0;
    *(float4*)vf1 = *(const float4*)(s0 + DH);
  };
  auto writeV = [&](int cur) {
#pragma unroll
    for (int e = 0; e < 4; ++e) Vt[cur][4 * dch + e][vp] = cvtpk(vf0[e], vf1[e]);
  };

  // ================= pass 1: l = sum(exp(s)), barrier-free =================
  float part[4] = {0.f, 0.f, 0.f, 0.f};
  int fs = 0;
  for (int kt = 0; kt <= kmax; ++kt) {
    f32x4 acc[4];
#pragma unroll
    for (int ct = 0; ct < 4; ++ct) acc[ct] = (f32x4){0.f, 0.f, 0.f, 0.f};
    qk_batch(kt, 0, acc);
    if (fs < 126) { fillStep(fs); fillStep(fs + 1); fs += 2; }
    qk_batch(kt, 1, acc);
#pragma unroll
    for (int ct = 0; ct < 4; ++ct)
#pragma unroll
      for (int r = 0; r < 4; ++r) {
        const int j = kt * 64 + 16 * ct + c;
        const int i = qrw + wr0 + 4 * g + r;
        part[r] += (j <= i) ? __expf(acc[ct][r] * 0.125f) : 0.f;
      }
  }
  while (fs < 126) { fillStep(fs); ++fs; }

  float rinv[4];
#pragma unroll
  for (int r = 0; r < 4; ++r) {
    float s = part[r];
    s += __shfl_xor(s, 1); s += __shfl_xor(s, 2);
    s += __shfl_xor(s, 4); s += __shfl_xor(s, 8);
    rinv[r] = 1.f / s;
  }

  // ================= pass 2: attn + PV (R4 protocol) =================
  loadK(0);
  loadV(0);
  f32x4 oacc[4];
#pragma unroll
  for (int ct = 0; ct < 4; ++ct) oacc[ct] = (f32x4){0.f, 0.f, 0.f, 0.f};

  for (int kt = 0; kt <= qb; ++kt) {
    const int cur = kt & 1;
    writeK(cur);
    writeV(cur);
    lbar();
    if (kt < qb) { loadK(kt + 1); loadV(kt + 1); }

    if (kt <= kmax) {
      f32x4 acc[4];
#pragma unroll
      for (int ct = 0; ct < 4; ++ct) acc[ct] = (f32x4){0.f, 0.f, 0.f, 0.f};
#pragma unroll
      for (int ks = 0; ks < 2; ++ks)
#pragma unroll
        for (int ct = 0; ct < 4; ++ct) {
          u16x8 u = *(const u16x8*)&Kl[cur][16 * ct + c][32 * ks + 8 * g];
          acc[ct] = __builtin_amdgcn_mfma_f32_16x16x32_bf16(aq[ks], __builtin_bit_cast(bf16x8, u), acc[ct], 0, 0, 0);
        }

      // mask, normalize, stash bf16 P in wave-private Pl slab
#pragma unroll
      for (int ct = 0; ct < 4; ++ct)
#pragma unroll
        for (int r = 0; r < 4; ++r) {
          const int jl = 16 * ct + c;
          const int i = qrw + wr0 + 4 * g + r;
          const int j = kt * 64 + jl;
          const float p = (j <= i) ? __expf(acc[ct][r] * 0.125f) * rinv[r] : 0.f;
          Pl[pOff + 4 * g + r][jl] = (unsigned short)cvtpk(p, p);
        }

      // attn store: wave-private readback, 4x dwordx4 per lane (issues early,
      // drains under the PV MFMAs below)
      {
        const int lr = lane >> 2, lc = lane & 3;
        u16x8 u0 = *(const u16x8*)&Pl[pOff + lr][lc * 16];
        u16x8 u1 = *(const u16x8*)&Pl[pOff + lr][lc * 16 + 8];
        float* dst = attnb + (size_t)(qrw + wr0 + lr) * NSEQ + kt * 64 + lc * 16;
        float4 f0, f1, f2, f3;
        f0.x = bf2f(u0[0]); f0.y = bf2f(u0[1]); f0.z = bf2f(u0[2]); f0.w = bf2f(u0[3]);
        f1.x = bf2f(u0[4]); f1.y = bf2f(u0[5]); f1.z = bf2f(u0[6]); f1.w = bf2f(u0[7]);
        f2.x = bf2f(u1[0]); f2.y = bf2f(u1[1]); f2.z = bf2f(u1[2]); f2.w = bf2f(u1[3]);
        f3.x = bf2f(u1[4]); f3.y = bf2f(u1[5]); f3.z = bf2f(u1[6]); f3.w = bf2f(u1[7]);
        ((float4*)dst)[0] = f0; ((float4*)dst)[1] = f1;
        ((float4*)dst)[2] = f2; ((float4*)dst)[3] = f3;
      }

      // immediate PV from wave-private Pl + Vt[cur]
      bf16x8 ap[2];
#pragma unroll
      for (int ks = 0; ks < 2; ++ks)
        ap[ks] = __builtin_bit_cast(bf16x8, *(const u16x8*)&Pl[pOff + c][32 * ks + 8 * g]);
#pragma unroll
      for (int ks = 0; ks < 2; ++ks)
#pragma unroll
        for (int ct = 0; ct < 4; ++ct) {
          u16x8 bv = *(const u16x8*)&Vt[cur][16 * ct + c][16 * ks + 4 * g];
          oacc[ct] = __builtin_amdgcn_mfma_f32_16x16x32_bf16(ap[ks], __builtin_bit_cast(bf16x8, bv), oacc[ct], 0, 0, 0);
        }
    }
  }

  // ---- out write ----
#pragma unroll
  for (int ct = 0; ct < 4; ++ct)
#pragma unroll
    for (int r = 0; r < 4; ++r) {
      const int i = qrw + wr0 + 4 * g + r;
      outb[(size_t)i * DH + 16 * ct + c] = oacc[ct][r];
    }
}

extern "C" void kernel_launch(void* const* d_in, const int* in_sizes, int n_in,
                              void* d_out, int out_size, void* d_ws, size_t ws_size,
                              hipStream_t stream) {
  (void)in_sizes; (void)n_in; (void)out_size; (void)d_ws; (void)ws_size;
  const float* q = (const float*)d_in[0];
  const float* k = (const float*)d_in[1];
  const float* v = (const float*)d_in[2];
  float* out = (float*)d_out;
  sdpa_fused<<<dim3(512), dim3(512), 0, stream>>>(q, k, v, out);
}

// Round 9
// 388.469 us; speedup vs baseline: 1.2663x; 1.2663x over previous
//
#include <hip/hip_runtime.h>

typedef float f32x4 __attribute__((ext_vector_type(4)));
typedef __bf16 bf16x8 __attribute__((ext_vector_type(8)));
typedef unsigned short u16x8 __attribute__((ext_vector_type(8)));
typedef unsigned int u32x4 __attribute__((ext_vector_type(4)));

#define NBH 16
#define NSEQ 4096
#define DH 64
#define NST 65

__device__ __forceinline__ unsigned int cvtpk(float lo, float hi) {
  unsigned int r;
  asm("v_cvt_pk_bf16_f32 %0, %1, %2" : "=v"(r) : "v"(lo), "v"(hi));
  return r;
}
__device__ __forceinline__ bf16x8 pk8(const float* f) {
  union { unsigned int u[4]; bf16x8 b; } x;
#pragma unroll
  for (int i = 0; i < 4; ++i) x.u[i] = cvtpk(f[2 * i], f[2 * i + 1]);
  return x.b;
}
__device__ __forceinline__ float bf2f(unsigned short h) {
  return __uint_as_float(((unsigned int)h) << 16);
}
__device__ __forceinline__ void lbar() {
  __builtin_amdgcn_sched_barrier(0);
  asm volatile("s_waitcnt lgkmcnt(0)" ::: "memory");
  __builtin_amdgcn_s_barrier();
  __builtin_amdgcn_sched_barrier(0);
}

// Fused causal SDPA, uniform 65-step schedule. Block owns complementary
// 64-row q-tiles {qa=qt, qb=63-qt}; all 8 waves work the SAME tile each step
// (steps 0..qa: tile A, kt=s; steps qa+1..64: tile B, kt=s-qa-1) -> every
// block has identical step count/work; zero CU imbalance. Wave pairs (w,w+4)
// split the 64 score-cols: wave w -> cols [32h,32h+32). PV split by k-half,
// merged once at the end. Zero-fill interleaved into pass 1.
__global__ __launch_bounds__(512, 4) void sdpa_fused(
    const float* __restrict__ qg, const float* __restrict__ kg,
    const float* __restrict__ vg, float* __restrict__ outg) {
  const int bid = blockIdx.x;
  const int xcd = bid & 7;
  const int ii = bid >> 3;       // 0..63
  const int hh = ii >> 5;        // head within XCD
  const int qt = ii & 31;
  const int b = 2 * xcd + hh;    // 2 heads per XCD
  const int qa = qt, qb = 63 - qt;

  const int tid = threadIdx.x;
  const int w = tid >> 6, lane = tid & 63;
  const int g = lane >> 4, c = lane & 15;
  const int pw = w & 3, hf = w >> 2;   // pair index, col-half
  const int wr0 = 16 * pw;             // rows within current tile
  const int ct0 = 2 * hf;              // first score-col block (of 4)
  const int jb0 = 32 * hf;             // col offset of this wave's half

  const float* qbp = qg + (size_t)b * NSEQ * DH;
  const float* kbp = kg + (size_t)b * NSEQ * DH;
  const float* vbp = vg + (size_t)b * NSEQ * DH;
  float* outb = outg + (size_t)b * NSEQ * DH;
  float* attnb = outg + (size_t)NBH * NSEQ * DH + (size_t)b * NSEQ * NSEQ;

  __shared__ union {
    struct {
      unsigned short Kl[2][64][72];
      unsigned int Vt[2][64][37];   // u32 = {bf16 V[2p][d], bf16 V[2p+1][d]}
      unsigned short Pl[64][72];
    } m;
    float ex[2][8][64];    // denominator exchange (overlays Kl)
    float mg[4][64][16];   // oacc merge (overlays Kl)
  } sm;

  // ---- Q fragments for BOTH tiles: row = q*64+wr0+c, k = 32ks+8g+e ----
  bf16x8 aqA[2], aqB[2];
  {
    const float* ra = qbp + (size_t)(qa * 64 + wr0 + c) * DH;
    const float* rb = qbp + (size_t)(qb * 64 + wr0 + c) * DH;
#pragma unroll
    for (int ks = 0; ks < 2; ++ks) {
      float f[8];
      *(float4*)f = *(const float4*)(ra + 32 * ks + 8 * g);
      *(float4*)(f + 4) = *(const float4*)(ra + 32 * ks + 8 * g + 4);
      aqA[ks] = pk8(f);
      *(float4*)f = *(const float4*)(rb + 32 * ks + 8 * g);
      *(float4*)(f + 4) = *(const float4*)(rb + 32 * ks + 8 * g + 4);
      aqB[ks] = pk8(f);
    }
  }

  // ---- staging maps ----
  const int kj = tid >> 3, kcs = tid & 7;   // K: row kj, 8-float chunk
  const int vp = tid >> 4, dch = tid & 15;  // V: row-pair vp, 4-dim chunk
  float kf[8], vf0[4], vf1[4];

  auto loadK = [&](int kt) {
    const float* s = kbp + (size_t)(kt * 64 + kj) * DH + kcs * 8;
    *(float4*)kf = ((const float4*)s)[0];
    *(float4*)(kf + 4) = ((const float4*)s)[1];
  };
  auto writeK = [&](int cur) {
    u32x4 u;
#pragma unroll
    for (int i = 0; i < 4; ++i) u[i] = cvtpk(kf[2 * i], kf[2 * i + 1]);
    *(u32x4*)&sm.m.Kl[cur][kj][kcs * 8] = u;
  };
  auto loadV = [&](int kt) {
    const float* s0 = vbp + (size_t)(kt * 64 + 2 * vp) * DH + dch * 4;
    *(float4*)vf0 = *(const float4*)s0;
    *(float4*)vf1 = *(const float4*)(s0 + DH);
  };
  auto writeV = [&](int cur) {
#pragma unroll
    for (int e = 0; e < 4; ++e) sm.m.Vt[cur][4 * dch + e][vp] = cvtpk(vf0[e], vf1[e]);
  };

  // ---- zero-fill: 4032 row-chunks (64 cols) per block, 32 chunks/step ----
  const int myChunk = 4 * w + g;
  auto fillStep = [&](int s) {
    const unsigned cid = (unsigned)(s * 32 + myChunk);   // 0..4031
    const unsigned pr = cid / 63u;
    const int t = (int)(cid - pr * 63u);
    int row, col64;
    if (t < 63 - qa) { row = qa * 64 + (int)pr; col64 = qa + 1 + t; }
    else             { row = qb * 64 + (int)pr; col64 = t + 1; }
    const float4 z = {0.f, 0.f, 0.f, 0.f};
    *(float4*)(attnb + (size_t)row * NSEQ + col64 * 64 + c * 4) = z;
  };

  // ================= pass 1: denominators =================
  float partA[4] = {0.f, 0.f, 0.f, 0.f};
  float partB[4] = {0.f, 0.f, 0.f, 0.f};
  loadK(0);
  int fs = 0;
  for (int s = 0; s < NST; ++s) {
    const int cur = s & 1;
    writeK(cur);
    lbar();
    if (s + 1 < NST) loadK((s + 1 <= qa) ? (s + 1) : (s - qa));
    if (fs < 126) { fillStep(fs); fillStep(fs + 1); fs += 2; }

    const bool isB = s > qa;
    const int kt = isB ? s - qa - 1 : s;
    f32x4 acc[2];
    acc[0] = (f32x4){0.f, 0.f, 0.f, 0.f};
    acc[1] = (f32x4){0.f, 0.f, 0.f, 0.f};
    if (isB) {
#pragma unroll
      for (int ks = 0; ks < 2; ++ks)
#pragma unroll
        for (int cc = 0; cc < 2; ++cc) {
          u16x8 u = *(const u16x8*)&sm.m.Kl[cur][16 * (ct0 + cc) + c][32 * ks + 8 * g];
          acc[cc] = __builtin_amdgcn_mfma_f32_16x16x32_bf16(aqB[ks], __builtin_bit_cast(bf16x8, u), acc[cc], 0, 0, 0);
        }
#pragma unroll
      for (int cc = 0; cc < 2; ++cc)
#pragma unroll
        for (int r = 0; r < 4; ++r) {
          const int j = kt * 64 + 16 * (ct0 + cc) + c;
          const int i = qb * 64 + wr0 + 4 * g + r;
          partB[r] += (j <= i) ? __expf(acc[cc][r] * 0.125f) : 0.f;
        }
    } else {
#pragma unroll
      for (int ks = 0; ks < 2; ++ks)
#pragma unroll
        for (int cc = 0; cc < 2; ++cc) {
          u16x8 u = *(const u16x8*)&sm.m.Kl[cur][16 * (ct0 + cc) + c][32 * ks + 8 * g];
          acc[cc] = __builtin_amdgcn_mfma_f32_16x16x32_bf16(aqA[ks], __builtin_bit_cast(bf16x8, u), acc[cc], 0, 0, 0);
        }
#pragma unroll
      for (int cc = 0; cc < 2; ++cc)
#pragma unroll
        for (int r = 0; r < 4; ++r) {
          const int j = kt * 64 + 16 * (ct0 + cc) + c;
          const int i = qa * 64 + wr0 + 4 * g + r;
          partA[r] += (j <= i) ? __expf(acc[cc][r] * 0.125f) : 0.f;
        }
    }
  }

  // reduce over the 16 c-lanes (each wave holds its col-half sums)
#pragma unroll
  for (int r = 0; r < 4; ++r) {
    float sA = partA[r], sB = partB[r];
    sA += __shfl_xor(sA, 1); sA += __shfl_xor(sA, 2);
    sA += __shfl_xor(sA, 4); sA += __shfl_xor(sA, 8);
    sB += __shfl_xor(sB, 1); sB += __shfl_xor(sB, 2);
    sB += __shfl_xor(sB, 4); sB += __shfl_xor(sB, 8);
    partA[r] = sA; partB[r] = sB;
  }

  // prefetch pass-2 first tiles while merging denominators
  loadK(0);
  loadV(0);

  __syncthreads();   // pass-1 Kl reads done; ex overlay safe
  if (c == 0) {
#pragma unroll
    for (int r = 0; r < 4; ++r) {
      sm.ex[0][w][wr0 + 4 * g + r] = partA[r];
      sm.ex[1][w][wr0 + 4 * g + r] = partB[r];
    }
  }
  __syncthreads();
  float rinvA[4], rinvB[4];
#pragma unroll
  for (int r = 0; r < 4; ++r) {
    rinvA[r] = 1.f / (partA[r] + sm.ex[0][w ^ 4][wr0 + 4 * g + r]);
    rinvB[r] = 1.f / (partB[r] + sm.ex[1][w ^ 4][wr0 + 4 * g + r]);
  }
  __syncthreads();   // ex reads done before pass-2 clobbers Kl

  // ================= pass 2: attn + PV =================
  f32x4 oA[4], oB[4];
#pragma unroll
  for (int ct = 0; ct < 4; ++ct) {
    oA[ct] = (f32x4){0.f, 0.f, 0.f, 0.f};
    oB[ct] = (f32x4){0.f, 0.f, 0.f, 0.f};
  }

  for (int s = 0; s < NST; ++s) {
    const int cur = s & 1;
    writeK(cur);
    writeV(cur);
    lbar();
    if (s + 1 < NST) {
      const int nk = (s + 1 <= qa) ? (s + 1) : (s - qa);
      loadK(nk);
      loadV(nk);
    }

    const bool isB = s > qa;
    const int kt = isB ? s - qa - 1 : s;
    const int qr0 = (isB ? qb : qa) * 64;

    f32x4 acc[2];
    acc[0] = (f32x4){0.f, 0.f, 0.f, 0.f};
    acc[1] = (f32x4){0.f, 0.f, 0.f, 0.f};
    if (isB) {
#pragma unroll
      for (int ks = 0; ks < 2; ++ks)
#pragma unroll
        for (int cc = 0; cc < 2; ++cc) {
          u16x8 u = *(const u16x8*)&sm.m.Kl[cur][16 * (ct0 + cc) + c][32 * ks + 8 * g];
          acc[cc] = __builtin_amdgcn_mfma_f32_16x16x32_bf16(aqB[ks], __builtin_bit_cast(bf16x8, u), acc[cc], 0, 0, 0);
        }
#pragma unroll
      for (int cc = 0; cc < 2; ++cc)
#pragma unroll
        for (int r = 0; r < 4; ++r) {
          const int jl = 16 * (ct0 + cc) + c;
          const int i = qr0 + wr0 + 4 * g + r;
          const float p = (kt * 64 + jl <= i) ? __expf(acc[cc][r] * 0.125f) * rinvB[r] : 0.f;
          sm.m.Pl[wr0 + 4 * g + r][jl] = (unsigned short)cvtpk(p, p);
        }
    } else {
#pragma unroll
      for (int ks = 0; ks < 2; ++ks)
#pragma unroll
        for (int cc = 0; cc < 2; ++cc) {
          u16x8 u = *(const u16x8*)&sm.m.Kl[cur][16 * (ct0 + cc) + c][32 * ks + 8 * g];
          acc[cc] = __builtin_amdgcn_mfma_f32_16x16x32_bf16(aqA[ks], __builtin_bit_cast(bf16x8, u), acc[cc], 0, 0, 0);
        }
#pragma unroll
      for (int cc = 0; cc < 2; ++cc)
#pragma unroll
        for (int r = 0; r < 4; ++r) {
          const int jl = 16 * (ct0 + cc) + c;
          const int i = qr0 + wr0 + 4 * g + r;
          const float p = (kt * 64 + jl <= i) ? __expf(acc[cc][r] * 0.125f) * rinvA[r] : 0.f;
          sm.m.Pl[wr0 + 4 * g + r][jl] = (unsigned short)cvtpk(p, p);
        }
    }

    // attn store: own 16x32 quarter, 2x dwordx4 per lane
    {
      const int lr = lane >> 2, lq = lane & 3;
      u16x8 u = *(const u16x8*)&sm.m.Pl[wr0 + lr][jb0 + lq * 8];
      float* dst = attnb + (size_t)(qr0 + wr0 + lr) * NSEQ + kt * 64 + jb0 + lq * 8;
      float4 f0, f1;
      f0.x = bf2f(u[0]); f0.y = bf2f(u[1]); f0.z = bf2f(u[2]); f0.w = bf2f(u[3]);
      f1.x = bf2f(u[4]); f1.y = bf2f(u[5]); f1.z = bf2f(u[6]); f1.w = bf2f(u[7]);
      ((float4*)dst)[0] = f0;
      ((float4*)dst)[1] = f1;
    }

    // PV over own k-half (k = jb0..jb0+32), private accumulator
    {
      bf16x8 ap = __builtin_bit_cast(bf16x8, *(const u16x8*)&sm.m.Pl[wr0 + c][jb0 + 8 * g]);
      if (isB) {
#pragma unroll
        for (int ct = 0; ct < 4; ++ct) {
          u16x8 bv = *(const u16x8*)&sm.m.Vt[cur][16 * ct + c][16 * hf + 4 * g];
          oB[ct] = __builtin_amdgcn_mfma_f32_16x16x32_bf16(ap, __builtin_bit_cast(bf16x8, bv), oB[ct], 0, 0, 0);
        }
      } else {
#pragma unroll
        for (int ct = 0; ct < 4; ++ct) {
          u16x8 bv = *(const u16x8*)&sm.m.Vt[cur][16 * ct + c][16 * hf + 4 * g];
          oA[ct] = __builtin_amdgcn_mfma_f32_16x16x32_bf16(ap, __builtin_bit_cast(bf16x8, bv), oA[ct], 0, 0, 0);
        }
      }
    }
  }

  // ---- merge k-halves of oA/oB across wave pairs, write out ----
  __syncthreads();
  if (hf) {
#pragma unroll
    for (int ct = 0; ct < 4; ++ct)
#pragma unroll
      for (int r = 0; r < 4; ++r) sm.mg[pw][lane][4 * ct + r] = oA[ct][r];
  }
  __syncthreads();
  if (!hf) {
#pragma unroll
    for (int ct = 0; ct < 4; ++ct)
#pragma unroll
      for (int r = 0; r < 4; ++r) oA[ct][r] += sm.mg[pw][lane][4 * ct + r];
  }
  __syncthreads();
  if (hf) {
#pragma unroll
    for (int ct = 0; ct < 4; ++ct)
#pragma unroll
      for (int r = 0; r < 4; ++r) sm.mg[pw][lane][4 * ct + r] = oB[ct][r];
  }
  __syncthreads();
  if (!hf) {
#pragma unroll
    for (int ct = 0; ct < 4; ++ct)
#pragma unroll
      for (int r = 0; r < 4; ++r) {
        oB[ct][r] += sm.mg[pw][lane][4 * ct + r];
        const int ia = qa * 64 + wr0 + 4 * g + r;
        const int ib = qb * 64 + wr0 + 4 * g + r;
        outb[(size_t)ia * DH + 16 * ct + c] = oA[ct][r];
        outb[(size_t)ib * DH + 16 * ct + c] = oB[ct][r];
      }
  }

  while (fs < 126) { fillStep(fs); ++fs; }
}

extern "C" void kernel_launch(void* const* d_in, const int* in_sizes, int n_in,
                              void* d_out, int out_size, void* d_ws, size_t ws_size,
                              hipStream_t stream) {
  (void)in_sizes; (void)n_in; (void)out_size; (void)d_ws; (void)ws_size;
  const float* q = (const float*)d_in[0];
  const float* k = (const float*)d_in[1];
  const float* v = (const float*)d_in[2];
  float* out = (float*)d_out;
  sdpa_fused<<<dim3(512), dim3(512), 0, stream>>>(q, k, v, out);
}